// Round 8
// baseline (1368.105 us; speedup 1.0000x reference)
//
#include <hip/hip_runtime.h>
#include <hip/hip_cooperative_groups.h>

namespace cg = cooperative_groups;

#define NN 20000     // nodes
#define NE 320000    // edges
#define NG 64        // graphs
#define DIN 128
#define DH 64
#define NH 8
#define HD 512       // NH*DH
#define NC 32
#define NBLK 1024
#define NTHR 256

typedef unsigned short ushort_t;
typedef unsigned int uint_t;

struct Params {
  const float* g_feats; const int* src; const int* dst; const int* gid;
  const float* W_in; const float* b_in;
  const float* Wsrc1; const float* bsrc1; const float* Wdst1; const float* bdst1;
  const float* attn1; const float* bias1;
  const float* Wsrc2; const float* bsrc2; const float* Wdst2; const float* bdst2;
  const float* attn2; const float* bias2;
  const float* Wh1; const float* bh1; const float* Wh2; const float* bh2;
  float* h0; float* h1; float* h2;
  ushort_t* fsb; float* fd;
  int* row_start; int* cursor; int* src_sorted; int* gs; int* counts;
  float* out;
};

__device__ __forceinline__ ushort_t f2bf(float f) {   // RNE float->bf16
  uint_t x = __float_as_uint(f);
  uint_t r = (x + 0x7fffu + ((x >> 16) & 1u)) >> 16;
  return (ushort_t)r;
}

template<int PAT>
__device__ __forceinline__ float swz(float v) {
  return __int_as_float(__builtin_amdgcn_ds_swizzle(__float_as_int(v), PAT));
}

// ---------- input linear tile: 16 rows of [NN,128]@[128,64]+b (256 thr) ----------
__device__ __forceinline__ void gemm_in_tile(const float* __restrict__ gf,
    const float* __restrict__ W_in, const float* __restrict__ b_in,
    float* __restrict__ h0, int tile) {
  __shared__ float AsIn[16][DIN];
  const int t = threadIdx.x;
  const int row0 = tile * 16;                 // 1250*16 == 20000 exact
  for (int i = t; i < 16 * DIN; i += NTHR)
    AsIn[i >> 7][i & 127] = gf[(size_t)(row0 + (i >> 7)) * DIN + (i & 127)];
  __syncthreads();
  const int c = t & 63, rg = t >> 6;          // 4 rows per thread
  float acc[4] = {0.f, 0.f, 0.f, 0.f};
  for (int k = 0; k < DIN; ++k) {
    float w = W_in[k * DH + c];
#pragma unroll
    for (int i = 0; i < 4; ++i) acc[i] += AsIn[rg * 4 + i][k] * w;
  }
  float b = b_in[c];
#pragma unroll
  for (int i = 0; i < 4; ++i)
    h0[(size_t)(row0 + rg * 4 + i) * DH + c] = acc[i] + b;
  __syncthreads();
}

// ---------- hidden linear tile: 16 rows x 512 cols; fs(bf16) or fd(fp32) ----------
__device__ __forceinline__ void pair_tile(const float* __restrict__ A,
    const float* __restrict__ Ws, const float* __restrict__ bs,
    const float* __restrict__ Wd, const float* __restrict__ bd,
    ushort_t* __restrict__ fsb, float* __restrict__ fd, int tile) {
  __shared__ float AsP[16][DH];
  const int t = threadIdx.x;
  const bool isFd = tile >= (NN / 16);
  const int bx = isFd ? tile - (NN / 16) : tile;
  const float* W = isFd ? Wd : Ws;
  const float* b = isFd ? bd : bs;
  const int row0 = bx * 16;
  {
    int idx = t * 4;                          // 256*4 = 1024 floats
    int r = idx >> 6, k = idx & 63;
    *(float4*)&AsP[r][k] = *(const float4*)&A[(size_t)(row0 + r) * DH + k];
  }
  __syncthreads();
  const int tc = t & 127;                     // col quad 4*tc
  const int tr = t >> 7;                      // rows tr*8 .. tr*8+7
  float acc[8][4];
#pragma unroll
  for (int r = 0; r < 8; ++r)
#pragma unroll
    for (int c = 0; c < 4; ++c) acc[r][c] = 0.f;
#pragma unroll 4
  for (int k = 0; k < DH; ++k) {
    float4 wv = *(const float4*)&W[k * HD + 4 * tc];
#pragma unroll
    for (int r = 0; r < 8; ++r) {
      float a = AsP[tr * 8 + r][k];
      acc[r][0] += a * wv.x; acc[r][1] += a * wv.y;
      acc[r][2] += a * wv.z; acc[r][3] += a * wv.w;
    }
  }
  float4 bv = *(const float4*)&b[4 * tc];
#pragma unroll
  for (int r = 0; r < 8; ++r) {
    int row = row0 + tr * 8 + r;
    float v0 = acc[r][0] + bv.x, v1 = acc[r][1] + bv.y;
    float v2 = acc[r][2] + bv.z, v3 = acc[r][3] + bv.w;
    if (!isFd) {
      ushort4 o;
      o.x = f2bf(v0); o.y = f2bf(v1); o.z = f2bf(v2); o.w = f2bf(v3);
      *(ushort4*)&fsb[(size_t)row * HD + 4 * tc] = o;
    } else {
      *(float4*)&fd[(size_t)row * HD + 4 * tc] = make_float4(v0, v1, v2, v3);
    }
  }
  __syncthreads();
}

// ---------- exclusive scan of counts (one 256-thr block) ----------
__device__ __forceinline__ void scan_block(const int* __restrict__ counts,
    int* __restrict__ row_start, int* __restrict__ cursor) {
  __shared__ int ps[NTHR];
  const int t = threadIdx.x;
  const int CH = (NN + NTHR - 1) / NTHR;      // 79
  int base = t * CH;
  int s = 0;
  for (int i = 0; i < CH; ++i) {
    int idx = base + i;
    if (idx < NN) s += counts[idx];
  }
  ps[t] = s;
  __syncthreads();
  for (int off = 1; off < NTHR; off <<= 1) {
    int v = (t >= off) ? ps[t - off] : 0;
    __syncthreads();
    ps[t] += v;
    __syncthreads();
  }
  int prefix = (t > 0) ? ps[t - 1] : 0;
  for (int i = 0; i < CH; ++i) {
    int idx = base + i;
    if (idx < NN) {
      row_start[idx] = prefix;
      cursor[idx] = prefix;
      prefix += counts[idx];
    }
  }
  if (t == NTHR - 1) row_start[NN] = ps[NTHR - 1];
}

// ---------- fused GATv2 node: wave = 1 edge x all 8 heads, 8 feats/lane ----------
__device__ __forceinline__ void gat_node(const ushort_t* __restrict__ fsb,
    const float* __restrict__ fdp, const int* __restrict__ src_sorted,
    const int* __restrict__ row_start, const float* __restrict__ attn,
    const float* __restrict__ bias, float* __restrict__ hout, int do_relu, int v) {
  __shared__ float s_acc[4][64][8];   // 8 KB
  __shared__ float s_m[4][64];        // 1 KB
  __shared__ float s_sum[4][64];      // 1 KB
  __shared__ float merged[HD];        // 2 KB
  const int t = threadIdx.x;
  const int lane = t & 63;
  const int w = t >> 6;                       // 4 waves, edge stride 4
  const int fi = lane * 8;                    // head = lane>>3, feats fi..fi+7
  float fdv[8], av[8];
  *(float4*)&fdv[0] = *(const float4*)&fdp[(size_t)v * HD + fi];
  *(float4*)&fdv[4] = *(const float4*)&fdp[(size_t)v * HD + fi + 4];
  *(float4*)&av[0]  = *(const float4*)&attn[fi];
  *(float4*)&av[4]  = *(const float4*)&attn[fi + 4];
  const int beg = row_start[v], end = row_start[v + 1];
  float m = -3.4e38f, sum = 0.f;
  float acc[8];
#pragma unroll
  for (int i = 0; i < 8; ++i) acc[i] = 0.f;
  int e = beg + w;
  for (; e + 4 < end; e += 8) {               // 2 edges per iter (e, e+4)
    int sA = src_sorted[e], sB = src_sorted[e + 4];
    uint4 uA = *(const uint4*)&fsb[(size_t)sA * HD + fi];
    uint4 uB = *(const uint4*)&fsb[(size_t)sB * HD + fi];
    float fA[8], fB[8];
    fA[0] = __uint_as_float(uA.x << 16); fA[1] = __uint_as_float(uA.x & 0xffff0000u);
    fA[2] = __uint_as_float(uA.y << 16); fA[3] = __uint_as_float(uA.y & 0xffff0000u);
    fA[4] = __uint_as_float(uA.z << 16); fA[5] = __uint_as_float(uA.z & 0xffff0000u);
    fA[6] = __uint_as_float(uA.w << 16); fA[7] = __uint_as_float(uA.w & 0xffff0000u);
    fB[0] = __uint_as_float(uB.x << 16); fB[1] = __uint_as_float(uB.x & 0xffff0000u);
    fB[2] = __uint_as_float(uB.y << 16); fB[3] = __uint_as_float(uB.y & 0xffff0000u);
    fB[4] = __uint_as_float(uB.z << 16); fB[5] = __uint_as_float(uB.z & 0xffff0000u);
    fB[6] = __uint_as_float(uB.w << 16); fB[7] = __uint_as_float(uB.w & 0xffff0000u);
    float pA = 0.f, pB = 0.f;
#pragma unroll
    for (int i = 0; i < 8; ++i) {
      float xA = fA[i] + fdv[i];
      float lA = fmaxf(xA, 0.f) + 0.2f * fminf(xA, 0.f);
      pA = fmaf(av[i], lA, pA);
      float xB = fB[i] + fdv[i];
      float lB = fmaxf(xB, 0.f) + 0.2f * fminf(xB, 0.f);
      pB = fmaf(av[i], lB, pB);
    }
    // reduce over 8-lane head group: xor 1,2,4 (single DS inst each)
    pA += swz<0x041F>(pA); pB += swz<0x041F>(pB);
    pA += swz<0x081F>(pA); pB += swz<0x081F>(pB);
    pA += swz<0x101F>(pA); pB += swz<0x101F>(pB);
    float mn = fmaxf(m, fmaxf(pA, pB));
    float scale = __expf(m - mn);
    float wA = __expf(pA - mn), wB = __expf(pB - mn);
    sum = fmaf(sum, scale, wA + wB);
#pragma unroll
    for (int i = 0; i < 8; ++i)
      acc[i] = fmaf(acc[i], scale, fmaf(wA, fA[i], wB * fB[i]));
    m = mn;
  }
  if (e < end) {                              // tail: single edge, wave-uniform
    int sA = src_sorted[e];
    uint4 uA = *(const uint4*)&fsb[(size_t)sA * HD + fi];
    float fA[8];
    fA[0] = __uint_as_float(uA.x << 16); fA[1] = __uint_as_float(uA.x & 0xffff0000u);
    fA[2] = __uint_as_float(uA.y << 16); fA[3] = __uint_as_float(uA.y & 0xffff0000u);
    fA[4] = __uint_as_float(uA.z << 16); fA[5] = __uint_as_float(uA.z & 0xffff0000u);
    fA[6] = __uint_as_float(uA.w << 16); fA[7] = __uint_as_float(uA.w & 0xffff0000u);
    float pA = 0.f;
#pragma unroll
    for (int i = 0; i < 8; ++i) {
      float xA = fA[i] + fdv[i];
      float lA = fmaxf(xA, 0.f) + 0.2f * fminf(xA, 0.f);
      pA = fmaf(av[i], lA, pA);
    }
    pA += swz<0x041F>(pA);
    pA += swz<0x081F>(pA);
    pA += swz<0x101F>(pA);
    float mn = fmaxf(m, pA);
    float scale = __expf(m - mn);
    float wA = __expf(pA - mn);
    sum = fmaf(sum, scale, wA);
#pragma unroll
    for (int i = 0; i < 8; ++i)
      acc[i] = fmaf(acc[i], scale, wA * fA[i]);
    m = mn;
  }
  // merge 4 wave states
  *(float4*)&s_acc[w][lane][0] = *(float4*)&acc[0];
  *(float4*)&s_acc[w][lane][4] = *(float4*)&acc[4];
  s_m[w][lane] = m;
  s_sum[w][lane] = sum;
  __syncthreads();
  if (w == 0) {
    float m0 = s_m[0][lane], m1 = s_m[1][lane], m2 = s_m[2][lane], m3 = s_m[3][lane];
    float M = fmaxf(fmaxf(m0, m1), fmaxf(m2, m3));
    float e0 = __expf(m0 - M), e1 = __expf(m1 - M);
    float e2 = __expf(m2 - M), e3 = __expf(m3 - M);
    float S = s_sum[0][lane] * e0 + s_sum[1][lane] * e1 +
              s_sum[2][lane] * e2 + s_sum[3][lane] * e3;
    float inv = 1.f / fmaxf(S, 1e-9f);
    float4 b0 = *(const float4*)&bias[fi];
    float4 b1 = *(const float4*)&bias[fi + 4];
    float bb[8] = {b0.x, b0.y, b0.z, b0.w, b1.x, b1.y, b1.z, b1.w};
#pragma unroll
    for (int i = 0; i < 8; ++i) {
      float a = s_acc[0][lane][i] * e0 + s_acc[1][lane][i] * e1 +
                s_acc[2][lane][i] * e2 + s_acc[3][lane][i] * e3;
      merged[fi + i] = a * inv + bb[i];
    }
  }
  __syncthreads();
  if (t < DH) {
    float s = 0.f;
#pragma unroll
    for (int hh = 0; hh < NH; ++hh) s += merged[hh * DH + t];
    s *= (1.f / NH);
    if (do_relu) s = fmaxf(s, 0.f);
    hout[(size_t)v * DH + t] = s;
  }
  __syncthreads();
}

// ---------- per-graph mean + MLP head + softmax ----------
__device__ __forceinline__ void head_block(const float* __restrict__ h2,
    const int* __restrict__ gsv, const float* __restrict__ Wh1,
    const float* __restrict__ bh1, const float* __restrict__ Wh2,
    const float* __restrict__ bh2, float* __restrict__ out, int g) {
  __shared__ float part[4][DH];
  __shared__ float hg[DH];
  __shared__ float hid[DH];
  __shared__ float logits[NC];
  const int t = threadIdx.x;
  const int f = t & 63, chunk = t >> 6;
  int start = gsv[g], stop = gsv[g + 1];
  float s = 0.f;
  for (int r = start + chunk; r < stop; r += 4) s += h2[(size_t)r * DH + f];
  part[chunk][f] = s;
  __syncthreads();
  if (t < DH) {
    float tot = part[0][t] + part[1][t] + part[2][t] + part[3][t];
    hg[t] = tot / fmaxf((float)(stop - start), 1.f);
  }
  __syncthreads();
  if (t < DH) {
    float a = 0.f;
    for (int k = 0; k < DH; ++k) a += hg[k] * Wh1[k * DH + t];
    hid[t] = fmaxf(a + bh1[t], 0.f);
  }
  __syncthreads();
  if (t < NC) {
    float l = 0.f;
    for (int k = 0; k < DH; ++k) l += hid[k] * Wh2[k * NC + t];
    logits[t] = l + bh2[t];
  }
  __syncthreads();
  if (t == 0) {
    float mx = logits[0];
    for (int i = 1; i < NC; ++i) mx = fmaxf(mx, logits[i]);
    float sm = 0.f;
    for (int i = 0; i < NC; ++i) {
      float wv = __expf(logits[i] - mx);
      logits[i] = wv;
      sm += wv;
    }
    float inv = 1.f / sm;
    for (int i = 0; i < NC; ++i) out[g * NC + i] = logits[i] * inv;
  }
}

// ---------------- the mega kernel: 8 phases, grid-wide syncs ----------------
__global__ __launch_bounds__(NTHR, 4) void k_mega(Params p) {
  cg::grid_group grid = cg::this_grid();
  const int bid = blockIdx.x;
  const int t = threadIdx.x;
  const int gtid = bid * NTHR + t;
  const int gstride = gridDim.x * NTHR;
  const int nblk = gridDim.x;

  // P0: zero counts + input GEMM (independent)
  for (int i = gtid; i < NN; i += gstride) p.counts[i] = 0;
  for (int tile = bid; tile < NN / 16; tile += nblk)
    gemm_in_tile(p.g_feats, p.W_in, p.b_in, p.h0, tile);
  grid.sync();

  // P1: degree histogram + graph boundaries (independent)
  for (int e = gtid; e < NE; e += gstride) atomicAdd(&p.counts[p.dst[e]], 1);
  for (int i = gtid; i <= NN; i += gstride) {
    if (i == 0) {
      for (int g = 0; g <= p.gid[0]; ++g) p.gs[g] = 0;
    } else if (i == NN) {
      for (int g = p.gid[NN - 1] + 1; g <= NG; ++g) p.gs[g] = NN;
    } else {
      int a = p.gid[i - 1], b = p.gid[i];
      for (int g = a + 1; g <= b; ++g) p.gs[g] = i;
    }
  }
  grid.sync();

  // P2: exclusive scan -> row_start/cursor
  if (bid == 0) scan_block(p.counts, p.row_start, p.cursor);
  grid.sync();

  // P3: CSR scatter + layer-1 GEMM pair (independent)
  for (int e = gtid; e < NE; e += gstride) {
    int pos = atomicAdd(&p.cursor[p.dst[e]], 1);
    p.src_sorted[pos] = p.src[e];
  }
  for (int tile = bid; tile < 2 * (NN / 16); tile += nblk)
    pair_tile(p.h0, p.Wsrc1, p.bsrc1, p.Wdst1, p.bdst1, p.fsb, p.fd, tile);
  grid.sync();

  // P4: GAT layer 1
  for (int v = bid; v < NN; v += nblk)
    gat_node(p.fsb, p.fd, p.src_sorted, p.row_start, p.attn1, p.bias1, p.h1, 1, v);
  grid.sync();

  // P5: layer-2 GEMM pair
  for (int tile = bid; tile < 2 * (NN / 16); tile += nblk)
    pair_tile(p.h1, p.Wsrc2, p.bsrc2, p.Wdst2, p.bdst2, p.fsb, p.fd, tile);
  grid.sync();

  // P6: GAT layer 2
  for (int v = bid; v < NN; v += nblk)
    gat_node(p.fsb, p.fd, p.src_sorted, p.row_start, p.attn2, p.bias2, p.h2, 0, v);
  grid.sync();

  // P7: readout + head
  if (bid < NG)
    head_block(p.h2, p.gs, p.Wh1, p.bh1, p.Wh2, p.bh2, p.out, bid);
}

// ================= fallback path: round-6 proven separate kernels =================
__global__ __launch_bounds__(256) void k_gemm_in(const float* __restrict__ A,
    const float* __restrict__ W, const float* __restrict__ b, float* __restrict__ out,
    int* __restrict__ counts) {
  if (blockIdx.x < 20) {
    for (int i = threadIdx.x; i < 1000; i += 256) counts[blockIdx.x * 1000 + i] = 0;
  }
  gemm_in_tile(A, W, b, out, blockIdx.x);
}

__global__ __launch_bounds__(512) void k_gemm64pair(const float* __restrict__ A,
    const float* __restrict__ Wsrc, const float* __restrict__ bsrc,
    const float* __restrict__ Wdst, const float* __restrict__ bdst,
    ushort_t* __restrict__ fsb, float* __restrict__ fd) {
  const int nb = NN / 16;
  bool isFd = blockIdx.x >= nb;
  int bx = isFd ? (blockIdx.x - nb) : blockIdx.x;
  const float* W = isFd ? Wdst : Wsrc;
  const float* b = isFd ? bdst : bsrc;
  __shared__ float As[16][DH];
  int tc = threadIdx.x & 127;
  int tr = threadIdx.x >> 7;
  int row0 = bx * 16;
  for (int i = threadIdx.x; i < 16 * DH; i += 512) {
    int r = i >> 6, k = i & 63;
    As[r][k] = A[(size_t)(row0 + r) * DH + k];
  }
  __syncthreads();
  float acc[4][4];
#pragma unroll
  for (int r = 0; r < 4; ++r)
#pragma unroll
    for (int c = 0; c < 4; ++c) acc[r][c] = 0.f;
#pragma unroll 4
  for (int k = 0; k < DH; ++k) {
    float4 wv = *(const float4*)&W[k * HD + 4 * tc];
    float a0 = As[tr * 4 + 0][k];
    float a1 = As[tr * 4 + 1][k];
    float a2 = As[tr * 4 + 2][k];
    float a3 = As[tr * 4 + 3][k];
    acc[0][0] += a0 * wv.x; acc[0][1] += a0 * wv.y; acc[0][2] += a0 * wv.z; acc[0][3] += a0 * wv.w;
    acc[1][0] += a1 * wv.x; acc[1][1] += a1 * wv.y; acc[1][2] += a1 * wv.z; acc[1][3] += a1 * wv.w;
    acc[2][0] += a2 * wv.x; acc[2][1] += a2 * wv.y; acc[2][2] += a2 * wv.z; acc[2][3] += a2 * wv.w;
    acc[3][0] += a3 * wv.x; acc[3][1] += a3 * wv.y; acc[3][2] += a3 * wv.z; acc[3][3] += a3 * wv.w;
  }
  float4 bv = *(const float4*)&b[4 * tc];
#pragma unroll
  for (int r = 0; r < 4; ++r) {
    int row = row0 + tr * 4 + r;
    float v0 = acc[r][0] + bv.x, v1 = acc[r][1] + bv.y;
    float v2 = acc[r][2] + bv.z, v3 = acc[r][3] + bv.w;
    if (!isFd) {
      ushort4 o;
      o.x = f2bf(v0); o.y = f2bf(v1); o.z = f2bf(v2); o.w = f2bf(v3);
      *(ushort4*)&fsb[(size_t)row * HD + 4 * tc] = o;
    } else {
      *(float4*)&fd[(size_t)row * HD + 4 * tc] = make_float4(v0, v1, v2, v3);
    }
  }
}

__global__ void k_hist(const int* __restrict__ dst, int* __restrict__ counts) {
  int e = blockIdx.x * blockDim.x + threadIdx.x;
  if (e < NE) atomicAdd(&counts[dst[e]], 1);
}

__global__ __launch_bounds__(256) void k_scan_gbound(const int* __restrict__ counts,
    int* __restrict__ row_start, int* __restrict__ cursor,
    const int* __restrict__ gid, int* __restrict__ gs) {
  if (blockIdx.x > 0) {
    int i = (blockIdx.x - 1) * 256 + threadIdx.x;
    if (i > NN) return;
    if (i == 0) {
      for (int g = 0; g <= gid[0]; ++g) gs[g] = 0;
    } else if (i == NN) {
      for (int g = gid[NN - 1] + 1; g <= NG; ++g) gs[g] = NN;
    } else {
      int a = gid[i - 1], b2 = gid[i];
      for (int g = a + 1; g <= b2; ++g) gs[g] = i;
    }
    return;
  }
  scan_block(counts, row_start, cursor);
}

__global__ void k_scatter(const int* __restrict__ dst, const int* __restrict__ src,
                          int* __restrict__ cursor, int* __restrict__ src_sorted) {
  int e = blockIdx.x * blockDim.x + threadIdx.x;
  if (e < NE) {
    int p = atomicAdd(&cursor[dst[e]], 1);
    src_sorted[p] = src[e];
  }
}

__global__ __launch_bounds__(256) void k_gat(const ushort_t* __restrict__ fsb,
    const float* __restrict__ fd, const int* __restrict__ src_sorted,
    const int* __restrict__ row_start, const float* __restrict__ attn,
    const float* __restrict__ bias, float* __restrict__ hout, int do_relu) {
  gat_node(fsb, fd, src_sorted, row_start, attn, bias, hout, do_relu, blockIdx.x);
}

__global__ __launch_bounds__(256) void k_head(const float* __restrict__ h2,
    const int* __restrict__ gs, const float* __restrict__ Wh1,
    const float* __restrict__ bh1, const float* __restrict__ Wh2,
    const float* __restrict__ bh2, float* __restrict__ out) {
  head_block(h2, gs, Wh1, bh1, Wh2, bh2, out, blockIdx.x);
}

extern "C" void kernel_launch(void* const* d_in, const int* in_sizes, int n_in,
                              void* d_out, int out_size, void* d_ws, size_t ws_size,
                              hipStream_t stream) {
  Params p;
  p.g_feats = (const float*)d_in[0];
  p.src     = (const int*)d_in[1];
  p.dst     = (const int*)d_in[2];
  p.gid     = (const int*)d_in[3];
  p.W_in    = (const float*)d_in[4];
  p.b_in    = (const float*)d_in[5];
  p.Wsrc1   = (const float*)d_in[6];
  p.bsrc1   = (const float*)d_in[7];
  p.Wdst1   = (const float*)d_in[8];
  p.bdst1   = (const float*)d_in[9];
  p.attn1   = (const float*)d_in[10];
  p.bias1   = (const float*)d_in[11];
  p.Wsrc2   = (const float*)d_in[12];
  p.bsrc2   = (const float*)d_in[13];
  p.Wdst2   = (const float*)d_in[14];
  p.bdst2   = (const float*)d_in[15];
  p.attn2   = (const float*)d_in[16];
  p.bias2   = (const float*)d_in[17];
  p.Wh1     = (const float*)d_in[18];
  p.bh1     = (const float*)d_in[19];
  p.Wh2     = (const float*)d_in[20];
  p.bh2     = (const float*)d_in[21];

  char* ws = (char*)d_ws;
  size_t off = 0;
  auto A = [&](size_t bytes) -> char* {
    char* q = ws + off;
    off = (off + bytes + 255) & ~(size_t)255;
    return q;
  };
  p.h0         = (float*)A((size_t)NN * DH * 4);
  p.h1         = (float*)A((size_t)NN * DH * 4);
  p.h2         = (float*)A((size_t)NN * DH * 4);
  p.fsb        = (ushort_t*)A((size_t)NN * HD * 2);
  p.fd         = (float*)A((size_t)NN * HD * 4);
  p.row_start  = (int*)A((size_t)(NN + 1) * 4);
  p.cursor     = (int*)A((size_t)NN * 4);
  p.src_sorted = (int*)A((size_t)NE * 4);
  p.gs         = (int*)A((size_t)(NG + 1) * 4);
  p.counts     = (int*)A((size_t)NN * 4);
  p.out        = (float*)d_out;

  void* args[] = {(void*)&p};
  hipError_t rc = hipLaunchCooperativeKernel((void*)k_mega, dim3(NBLK), dim3(NTHR),
                                             args, 0, stream);
  if (rc != hipSuccess) {
    // deterministic fallback: proven separate-kernel pipeline
    const int nb16 = NN / 16;
    k_gemm_in<<<nb16, 256, 0, stream>>>(p.g_feats, p.W_in, p.b_in, p.h0, p.counts);
    k_hist<<<(NE + 255) / 256, 256, 0, stream>>>(p.dst, p.counts);
    k_scan_gbound<<<1 + (NN + 256) / 256, 256, 0, stream>>>(p.counts, p.row_start,
                                                            p.cursor, p.gid, p.gs);
    k_scatter<<<(NE + 255) / 256, 256, 0, stream>>>(p.dst, p.src, p.cursor, p.src_sorted);
    k_gemm64pair<<<2 * nb16, 512, 0, stream>>>(p.h0, p.Wsrc1, p.bsrc1, p.Wdst1,
                                               p.bdst1, p.fsb, p.fd);
    k_gat<<<NN, 256, 0, stream>>>(p.fsb, p.fd, p.src_sorted, p.row_start,
                                  p.attn1, p.bias1, p.h1, 1);
    k_gemm64pair<<<2 * nb16, 512, 0, stream>>>(p.h1, p.Wsrc2, p.bsrc2, p.Wdst2,
                                               p.bdst2, p.fsb, p.fd);
    k_gat<<<NN, 256, 0, stream>>>(p.fsb, p.fd, p.src_sorted, p.row_start,
                                  p.attn2, p.bias2, p.h2, 0);
    k_head<<<NG, 256, 0, stream>>>(p.h2, p.gs, p.Wh1, p.bh1, p.Wh2, p.bh2, p.out);
  }
}

// Round 10
// 398.971 us; speedup vs baseline: 3.4291x; 3.4291x over previous
//
#include <hip/hip_runtime.h>

#define NN 20000     // nodes
#define NE 320000    // edges
#define NG 64        // graphs
#define DIN 128
#define DH 64
#define NH 8
#define HD 512       // NH*DH
#define NC 32

typedef unsigned short ushort_t;
typedef unsigned int uint_t;

__device__ __forceinline__ ushort_t f2bf(float f) {   // RNE float->bf16
  uint_t x = __float_as_uint(f);
  uint_t r = (x + 0x7fffu + ((x >> 16) & 1u)) >> 16;
  return (ushort_t)r;
}

template<int PAT>
__device__ __forceinline__ float swz(float v) {
  return __int_as_float(__builtin_amdgcn_ds_swizzle(__float_as_int(v), PAT));
}

// ---------- input linear tile: 16 rows of [NN,128]@[128,64]+b (256 thr) ----------
__device__ __forceinline__ void gemm_in_tile(const float* __restrict__ gf,
    const float* __restrict__ W_in, const float* __restrict__ b_in,
    float* __restrict__ h0, int tile) {
  __shared__ float AsIn[16][DIN];
  const int t = threadIdx.x;
  const int row0 = tile * 16;                 // 1250*16 == 20000 exact
  for (int i = t; i < 16 * DIN; i += 256)
    AsIn[i >> 7][i & 127] = gf[(size_t)(row0 + (i >> 7)) * DIN + (i & 127)];
  __syncthreads();
  const int c = t & 63, rg = t >> 6;          // 4 rows per thread
  float acc[4] = {0.f, 0.f, 0.f, 0.f};
  for (int k = 0; k < DIN; ++k) {
    float w = W_in[k * DH + c];
#pragma unroll
    for (int i = 0; i < 4; ++i) acc[i] += AsIn[rg * 4 + i][k] * w;
  }
  float b = b_in[c];
#pragma unroll
  for (int i = 0; i < 4; ++i)
    h0[(size_t)(row0 + rg * 4 + i) * DH + c] = acc[i] + b;
}

// ---------- hidden linear tile: 16 rows x 512 cols; fs(bf16) or fd(fp32) ----------
__device__ __forceinline__ void pair_tile(const float* __restrict__ A,
    const float* __restrict__ Ws, const float* __restrict__ bs,
    const float* __restrict__ Wd, const float* __restrict__ bd,
    ushort_t* __restrict__ fsb, float* __restrict__ fd, int tile) {
  __shared__ float AsP[16][DH];
  const int t = threadIdx.x;
  const bool isFd = tile >= (NN / 16);
  const int bx = isFd ? tile - (NN / 16) : tile;
  const float* W = isFd ? Wd : Ws;
  const float* b = isFd ? bd : bs;
  const int row0 = bx * 16;
  {
    int idx = t * 4;                          // 256*4 = 1024 floats
    int r = idx >> 6, k = idx & 63;
    *(float4*)&AsP[r][k] = *(const float4*)&A[(size_t)(row0 + r) * DH + k];
  }
  __syncthreads();
  const int tc = t & 127;                     // col quad 4*tc
  const int tr = t >> 7;                      // rows tr*8 .. tr*8+7
  float acc[8][4];
#pragma unroll
  for (int r = 0; r < 8; ++r)
#pragma unroll
    for (int c = 0; c < 4; ++c) acc[r][c] = 0.f;
#pragma unroll 4
  for (int k = 0; k < DH; ++k) {
    float4 wv = *(const float4*)&W[k * HD + 4 * tc];
#pragma unroll
    for (int r = 0; r < 8; ++r) {
      float a = AsP[tr * 8 + r][k];
      acc[r][0] += a * wv.x; acc[r][1] += a * wv.y;
      acc[r][2] += a * wv.z; acc[r][3] += a * wv.w;
    }
  }
  float4 bv = *(const float4*)&b[4 * tc];
#pragma unroll
  for (int r = 0; r < 8; ++r) {
    int row = row0 + tr * 8 + r;
    float v0 = acc[r][0] + bv.x, v1 = acc[r][1] + bv.y;
    float v2 = acc[r][2] + bv.z, v3 = acc[r][3] + bv.w;
    if (!isFd) {
      ushort4 o;
      o.x = f2bf(v0); o.y = f2bf(v1); o.z = f2bf(v2); o.w = f2bf(v3);
      *(ushort4*)&fsb[(size_t)row * HD + 4 * tc] = o;
    } else {
      *(float4*)&fd[(size_t)row * HD + 4 * tc] = make_float4(v0, v1, v2, v3);
    }
  }
}

// ---------- P0: blocks 0..1249 input GEMM | 1250..2499 hist | 2500.. gbound ------
__global__ __launch_bounds__(256) void k_pre(const float* __restrict__ gf,
    const float* __restrict__ W_in, const float* __restrict__ b_in,
    float* __restrict__ h0, const int* __restrict__ dst, int* __restrict__ counts,
    const int* __restrict__ gid, int* __restrict__ gs) {
  const int bid = blockIdx.x;
  if (bid < NN / 16) {
    gemm_in_tile(gf, W_in, b_in, h0, bid);
  } else if (bid < NN / 16 + NE / 256) {
    int e = (bid - NN / 16) * 256 + threadIdx.x;
    atomicAdd(&counts[dst[e]], 1);
  } else {
    int i = (bid - (NN / 16 + NE / 256)) * 256 + threadIdx.x;
    if (i > NN) return;
    if (i == 0) {
      for (int g = 0; g <= gid[0]; ++g) gs[g] = 0;
    } else if (i == NN) {
      for (int g = gid[NN - 1] + 1; g <= NG; ++g) gs[g] = NN;
    } else {
      int a = gid[i - 1], b2 = gid[i];
      for (int g = a + 1; g <= b2; ++g) gs[g] = i;
    }
  }
}

// ---------- exclusive scan of counts (one 256-thr block) ----------
__global__ __launch_bounds__(256) void k_scan(const int* __restrict__ counts,
    int* __restrict__ row_start, int* __restrict__ cursor) {
  __shared__ int ps[256];
  const int t = threadIdx.x;
  const int CH = (NN + 255) / 256;            // 79
  int base = t * CH;
  int s = 0;
  for (int i = 0; i < CH; ++i) {
    int idx = base + i;
    if (idx < NN) s += counts[idx];
  }
  ps[t] = s;
  __syncthreads();
  for (int off = 1; off < 256; off <<= 1) {
    int v = (t >= off) ? ps[t - off] : 0;
    __syncthreads();
    ps[t] += v;
    __syncthreads();
  }
  int prefix = (t > 0) ? ps[t - 1] : 0;
  for (int i = 0; i < CH; ++i) {
    int idx = base + i;
    if (idx < NN) {
      row_start[idx] = prefix;
      cursor[idx] = prefix;
      prefix += counts[idx];
    }
  }
  if (t == 255) row_start[NN] = ps[255];
}

// ---------- P3: blocks 0..2499 layer-1 GEMM pair | 2500..3749 CSR scatter ----------
__global__ __launch_bounds__(256) void k_scatpair(const float* __restrict__ A,
    const float* __restrict__ Ws, const float* __restrict__ bs,
    const float* __restrict__ Wd, const float* __restrict__ bd,
    ushort_t* __restrict__ fsb, float* __restrict__ fd,
    const int* __restrict__ dst, const int* __restrict__ src,
    int* __restrict__ cursor, int* __restrict__ src_sorted) {
  const int bid = blockIdx.x;
  if (bid < 2 * (NN / 16)) {
    pair_tile(A, Ws, bs, Wd, bd, fsb, fd, bid);
  } else {
    int e = (bid - 2 * (NN / 16)) * 256 + threadIdx.x;
    int p = atomicAdd(&cursor[dst[e]], 1);
    src_sorted[p] = src[e];
  }
}

// ---------- layer-2 GEMM pair ----------
__global__ __launch_bounds__(256) void k_pair(const float* __restrict__ A,
    const float* __restrict__ Ws, const float* __restrict__ bs,
    const float* __restrict__ Wd, const float* __restrict__ bd,
    ushort_t* __restrict__ fsb, float* __restrict__ fd) {
  pair_tile(A, Ws, bs, Wd, bd, fsb, fd, blockIdx.x);
}

// ---------- fused GATv2: ONE WAVE PER NODE, lane = 8 contiguous bf16 feats --------
// No LDS, no barriers. Edge gather = contiguous 1KB row (dwordx4/lane).
// Score: 8-elem dot/lane + 3-step 8-lane swizzle reduce. Head-mean: stride-8
// lane butterfly (swz xor8, xor16, shfl xor32).
__global__ __launch_bounds__(256) void k_gat(const ushort_t* __restrict__ fsb,
    const float* __restrict__ fd, const int* __restrict__ src_sorted,
    const int* __restrict__ row_start, const float* __restrict__ attn,
    const float* __restrict__ bias, float* __restrict__ hout, int do_relu) {
  const int lane = threadIdx.x & 63;
  const int v = blockIdx.x * 4 + (threadIdx.x >> 6);
  const int fi = lane * 8;                    // head = lane>>3
  float fdv[8], av[8];
  *(float4*)&fdv[0] = *(const float4*)&fd[(size_t)v * HD + fi];
  *(float4*)&fdv[4] = *(const float4*)&fd[(size_t)v * HD + fi + 4];
  *(float4*)&av[0]  = *(const float4*)&attn[fi];
  *(float4*)&av[4]  = *(const float4*)&attn[fi + 4];
  int e = row_start[v];
  const int end = row_start[v + 1];
  float m = -3.4e38f, sum = 0.f;
  float acc[8];
#pragma unroll
  for (int i = 0; i < 8; ++i) acc[i] = 0.f;
  for (; e + 1 < end; e += 2) {               // 2 edges per iter
    int sA = src_sorted[e], sB = src_sorted[e + 1];
    uint4 uA = *(const uint4*)&fsb[(size_t)sA * HD + fi];
    uint4 uB = *(const uint4*)&fsb[(size_t)sB * HD + fi];
    float fA[8], fB[8];
    fA[0] = __uint_as_float(uA.x << 16); fA[1] = __uint_as_float(uA.x & 0xffff0000u);
    fA[2] = __uint_as_float(uA.y << 16); fA[3] = __uint_as_float(uA.y & 0xffff0000u);
    fA[4] = __uint_as_float(uA.z << 16); fA[5] = __uint_as_float(uA.z & 0xffff0000u);
    fA[6] = __uint_as_float(uA.w << 16); fA[7] = __uint_as_float(uA.w & 0xffff0000u);
    fB[0] = __uint_as_float(uB.x << 16); fB[1] = __uint_as_float(uB.x & 0xffff0000u);
    fB[2] = __uint_as_float(uB.y << 16); fB[3] = __uint_as_float(uB.y & 0xffff0000u);
    fB[4] = __uint_as_float(uB.z << 16); fB[5] = __uint_as_float(uB.z & 0xffff0000u);
    fB[6] = __uint_as_float(uB.w << 16); fB[7] = __uint_as_float(uB.w & 0xffff0000u);
    float pA = 0.f, pB = 0.f;
#pragma unroll
    for (int i = 0; i < 8; ++i) {
      float xA = fA[i] + fdv[i];
      float lA = fmaxf(xA, 0.f) + 0.2f * fminf(xA, 0.f);
      pA = fmaf(av[i], lA, pA);
      float xB = fB[i] + fdv[i];
      float lB = fmaxf(xB, 0.f) + 0.2f * fminf(xB, 0.f);
      pB = fmaf(av[i], lB, pB);
    }
    pA += swz<0x041F>(pA); pB += swz<0x041F>(pB);   // xor 1
    pA += swz<0x081F>(pA); pB += swz<0x081F>(pB);   // xor 2
    pA += swz<0x101F>(pA); pB += swz<0x101F>(pB);   // xor 4
    float mn = fmaxf(m, fmaxf(pA, pB));
    float scale = __expf(m - mn);
    float wA = __expf(pA - mn), wB = __expf(pB - mn);
    sum = fmaf(sum, scale, wA + wB);
#pragma unroll
    for (int i = 0; i < 8; ++i)
      acc[i] = fmaf(acc[i], scale, fmaf(wA, fA[i], wB * fB[i]));
    m = mn;
  }
  if (e < end) {                              // tail edge (wave-uniform)
    int sA = src_sorted[e];
    uint4 uA = *(const uint4*)&fsb[(size_t)sA * HD + fi];
    float fA[8];
    fA[0] = __uint_as_float(uA.x << 16); fA[1] = __uint_as_float(uA.x & 0xffff0000u);
    fA[2] = __uint_as_float(uA.y << 16); fA[3] = __uint_as_float(uA.y & 0xffff0000u);
    fA[4] = __uint_as_float(uA.z << 16); fA[5] = __uint_as_float(uA.z & 0xffff0000u);
    fA[6] = __uint_as_float(uA.w << 16); fA[7] = __uint_as_float(uA.w & 0xffff0000u);
    float pA = 0.f;
#pragma unroll
    for (int i = 0; i < 8; ++i) {
      float xA = fA[i] + fdv[i];
      float lA = fmaxf(xA, 0.f) + 0.2f * fminf(xA, 0.f);
      pA = fmaf(av[i], lA, pA);
    }
    pA += swz<0x041F>(pA);
    pA += swz<0x081F>(pA);
    pA += swz<0x101F>(pA);
    float mn = fmaxf(m, pA);
    float scale = __expf(m - mn);
    float wA = __expf(pA - mn);
    sum = fmaf(sum, scale, wA);
#pragma unroll
    for (int i = 0; i < 8; ++i)
      acc[i] = fmaf(acc[i], scale, wA * fA[i]);
  }
  float inv = 1.f / fmaxf(sum, 1e-9f);
  float outv[8];
#pragma unroll
  for (int i = 0; i < 8; ++i) outv[i] = fmaf(acc[i], inv, bias[fi + i]);
  // head-mean: sum across stride-8 lanes (same feat class), then /8
#pragma unroll
  for (int i = 0; i < 8; ++i) {
    outv[i] += swz<0x201F>(outv[i]);          // xor 8
    outv[i] += swz<0x401F>(outv[i]);          // xor 16
    outv[i] += __shfl_xor(outv[i], 32);
    outv[i] *= 0.125f;
    if (do_relu) outv[i] = fmaxf(outv[i], 0.f);
  }
  if (lane < 8) {                             // lane c holds feats 8c..8c+7
    *(float4*)&hout[(size_t)v * DH + lane * 8]     = make_float4(outv[0], outv[1], outv[2], outv[3]);
    *(float4*)&hout[(size_t)v * DH + lane * 8 + 4] = make_float4(outv[4], outv[5], outv[6], outv[7]);
  }
}

// ---------- per-graph mean + MLP head + softmax ----------
__global__ __launch_bounds__(256) void k_head(const float* __restrict__ h2,
    const int* __restrict__ gsv, const float* __restrict__ Wh1,
    const float* __restrict__ bh1, const float* __restrict__ Wh2,
    const float* __restrict__ bh2, float* __restrict__ out) {
  __shared__ float part[4][DH];
  __shared__ float hg[DH];
  __shared__ float hid[DH];
  __shared__ float logits[NC];
  const int g = blockIdx.x;
  const int t = threadIdx.x;
  const int f = t & 63, chunk = t >> 6;
  int start = gsv[g], stop = gsv[g + 1];
  float s = 0.f;
  for (int r = start + chunk; r < stop; r += 4) s += h2[(size_t)r * DH + f];
  part[chunk][f] = s;
  __syncthreads();
  if (t < DH) {
    float tot = part[0][t] + part[1][t] + part[2][t] + part[3][t];
    hg[t] = tot / fmaxf((float)(stop - start), 1.f);
  }
  __syncthreads();
  if (t < DH) {
    float a = 0.f;
    for (int k = 0; k < DH; ++k) a += hg[k] * Wh1[k * DH + t];
    hid[t] = fmaxf(a + bh1[t], 0.f);
  }
  __syncthreads();
  if (t < NC) {
    float l = 0.f;
    for (int k = 0; k < DH; ++k) l += hid[k] * Wh2[k * NC + t];
    logits[t] = l + bh2[t];
  }
  __syncthreads();
  if (t == 0) {
    float mx = logits[0];
    for (int i = 1; i < NC; ++i) mx = fmaxf(mx, logits[i]);
    float sm = 0.f;
    for (int i = 0; i < NC; ++i) {
      float wv = __expf(logits[i] - mx);
      logits[i] = wv;
      sm += wv;
    }
    float inv = 1.f / sm;
    for (int i = 0; i < NC; ++i) out[g * NC + i] = logits[i] * inv;
  }
}

extern "C" void kernel_launch(void* const* d_in, const int* in_sizes, int n_in,
                              void* d_out, int out_size, void* d_ws, size_t ws_size,
                              hipStream_t stream) {
  const float* g_feats = (const float*)d_in[0];
  const int*   src     = (const int*)d_in[1];
  const int*   dst     = (const int*)d_in[2];
  const int*   gid     = (const int*)d_in[3];
  const float* W_in    = (const float*)d_in[4];
  const float* b_in    = (const float*)d_in[5];
  const float* Wsrc1   = (const float*)d_in[6];
  const float* bsrc1   = (const float*)d_in[7];
  const float* Wdst1   = (const float*)d_in[8];
  const float* bdst1   = (const float*)d_in[9];
  const float* attn1   = (const float*)d_in[10];
  const float* bias1   = (const float*)d_in[11];
  const float* Wsrc2   = (const float*)d_in[12];
  const float* bsrc2   = (const float*)d_in[13];
  const float* Wdst2   = (const float*)d_in[14];
  const float* bdst2   = (const float*)d_in[15];
  const float* attn2   = (const float*)d_in[16];
  const float* bias2   = (const float*)d_in[17];
  const float* Wh1     = (const float*)d_in[18];
  const float* bh1     = (const float*)d_in[19];
  const float* Wh2     = (const float*)d_in[20];
  const float* bh2     = (const float*)d_in[21];

  char* ws = (char*)d_ws;
  size_t off = 0;
  auto A = [&](size_t bytes) -> char* {
    char* q = ws + off;
    off = (off + bytes + 255) & ~(size_t)255;
    return q;
  };
  float*    h0         = (float*)A((size_t)NN * DH * 4);
  float*    h1         = (float*)A((size_t)NN * DH * 4);
  float*    h2         = (float*)A((size_t)NN * DH * 4);
  ushort_t* fsb        = (ushort_t*)A((size_t)NN * HD * 2);
  float*    fd         = (float*)A((size_t)NN * HD * 4);
  int*      row_start  = (int*)A((size_t)(NN + 1) * 4);
  int*      cursor     = (int*)A((size_t)NN * 4);
  int*      src_sorted = (int*)A((size_t)NE * 4);
  int*      gs         = (int*)A((size_t)(NG + 1) * 4);
  int*      counts     = (int*)A((size_t)NN * 4);

  const int nb16 = NN / 16;                   // 1250
  const int histb = NE / 256;                 // 1250
  const int gbb = (NN + 256) / 256;           // 79

  hipMemsetAsync(counts, 0, (size_t)NN * 4, stream);

  k_pre<<<nb16 + histb + gbb, 256, 0, stream>>>(g_feats, W_in, b_in, h0,
                                                dst, counts, gid, gs);
  k_scan<<<1, 256, 0, stream>>>(counts, row_start, cursor);
  k_scatpair<<<2 * nb16 + histb, 256, 0, stream>>>(h0, Wsrc1, bsrc1, Wdst1, bdst1,
                                                   fsb, fd, dst, src, cursor, src_sorted);
  k_gat<<<NN / 4, 256, 0, stream>>>(fsb, fd, src_sorted, row_start, attn1, bias1, h1, 1);
  k_pair<<<2 * nb16, 256, 0, stream>>>(h1, Wsrc2, bsrc2, Wdst2, bdst2, fsb, fd);
  k_gat<<<NN / 4, 256, 0, stream>>>(fsb, fd, src_sorted, row_start, attn2, bias2, h2, 0);
  k_head<<<NG, 256, 0, stream>>>(h2, gs, Wh1, bh1, Wh2, bh2, (float*)d_out);
}

// Round 11
// 341.799 us; speedup vs baseline: 4.0027x; 1.1673x over previous
//
#include <hip/hip_runtime.h>

#define NN 20000     // nodes
#define NE 320000    // edges
#define NG 64        // graphs
#define DIN 128
#define DH 64
#define NH 8
#define HD 512       // NH*DH
#define NC 32

typedef unsigned short ushort_t;
typedef unsigned int uint_t;

__device__ __forceinline__ ushort_t f2bf(float f) {   // RNE float->bf16
  uint_t x = __float_as_uint(f);
  uint_t r = (x + 0x7fffu + ((x >> 16) & 1u)) >> 16;
  return (ushort_t)r;
}

template<int PAT>
__device__ __forceinline__ float swz(float v) {
  return __int_as_float(__builtin_amdgcn_ds_swizzle(__float_as_int(v), PAT));
}

// ---------- input linear tile: 16 rows of [NN,128]@[128,64]+b (256 thr) ----------
__device__ __forceinline__ void gemm_in_tile(const float* __restrict__ gf,
    const float* __restrict__ W_in, const float* __restrict__ b_in,
    float* __restrict__ h0, int tile) {
  __shared__ float AsIn[16][DIN];
  const int t = threadIdx.x;
  const int row0 = tile * 16;                 // 1250*16 == 20000 exact
  for (int i = t; i < 16 * DIN; i += 256)
    AsIn[i >> 7][i & 127] = gf[(size_t)(row0 + (i >> 7)) * DIN + (i & 127)];
  __syncthreads();
  const int c = t & 63, rg = t >> 6;          // 4 rows per thread
  float acc[4] = {0.f, 0.f, 0.f, 0.f};
  for (int k = 0; k < DIN; ++k) {
    float w = W_in[k * DH + c];
#pragma unroll
    for (int i = 0; i < 4; ++i) acc[i] += AsIn[rg * 4 + i][k] * w;
  }
  float b = b_in[c];
#pragma unroll
  for (int i = 0; i < 4; ++i)
    h0[(size_t)(row0 + rg * 4 + i) * DH + c] = acc[i] + b;
}

// ---------- hidden linear tile: 16 rows x 512 cols; fs(bf16) or fd(fp32) ----------
__device__ __forceinline__ void pair_tile(const float* __restrict__ A,
    const float* __restrict__ Ws, const float* __restrict__ bs,
    const float* __restrict__ Wd, const float* __restrict__ bd,
    ushort_t* __restrict__ fsb, float* __restrict__ fd, int tile) {
  __shared__ float AsP[16][DH];
  const int t = threadIdx.x;
  const bool isFd = tile >= (NN / 16);
  const int bx = isFd ? tile - (NN / 16) : tile;
  const float* W = isFd ? Wd : Ws;
  const float* b = isFd ? bd : bs;
  const int row0 = bx * 16;
  {
    int idx = t * 4;                          // 256*4 = 1024 floats
    int r = idx >> 6, k = idx & 63;
    *(float4*)&AsP[r][k] = *(const float4*)&A[(size_t)(row0 + r) * DH + k];
  }
  __syncthreads();
  const int tc = t & 127;                     // col quad 4*tc
  const int tr = t >> 7;                      // rows tr*8 .. tr*8+7
  float acc[8][4];
#pragma unroll
  for (int r = 0; r < 8; ++r)
#pragma unroll
    for (int c = 0; c < 4; ++c) acc[r][c] = 0.f;
#pragma unroll 4
  for (int k = 0; k < DH; ++k) {
    float4 wv = *(const float4*)&W[k * HD + 4 * tc];
#pragma unroll
    for (int r = 0; r < 8; ++r) {
      float a = AsP[tr * 8 + r][k];
      acc[r][0] += a * wv.x; acc[r][1] += a * wv.y;
      acc[r][2] += a * wv.z; acc[r][3] += a * wv.w;
    }
  }
  float4 bv = *(const float4*)&b[4 * tc];
#pragma unroll
  for (int r = 0; r < 8; ++r) {
    int row = row0 + tr * 8 + r;
    float v0 = acc[r][0] + bv.x, v1 = acc[r][1] + bv.y;
    float v2 = acc[r][2] + bv.z, v3 = acc[r][3] + bv.w;
    if (!isFd) {
      ushort4 o;
      o.x = f2bf(v0); o.y = f2bf(v1); o.z = f2bf(v2); o.w = f2bf(v3);
      *(ushort4*)&fsb[(size_t)row * HD + 4 * tc] = o;
    } else {
      *(float4*)&fd[(size_t)row * HD + 4 * tc] = make_float4(v0, v1, v2, v3);
    }
  }
}

// ---------- P0: blocks 0..1249 input GEMM | 1250..2499 hist | 2500.. gbound ------
__global__ __launch_bounds__(256) void k_pre(const float* __restrict__ gf,
    const float* __restrict__ W_in, const float* __restrict__ b_in,
    float* __restrict__ h0, const int* __restrict__ dst, int* __restrict__ counts,
    const int* __restrict__ gid, int* __restrict__ gs) {
  const int bid = blockIdx.x;
  if (bid < NN / 16) {
    gemm_in_tile(gf, W_in, b_in, h0, bid);
  } else if (bid < NN / 16 + NE / 256) {
    int e = (bid - NN / 16) * 256 + threadIdx.x;
    atomicAdd(&counts[dst[e]], 1);
  } else {
    int i = (bid - (NN / 16 + NE / 256)) * 256 + threadIdx.x;
    if (i > NN) return;
    if (i == 0) {
      for (int g = 0; g <= gid[0]; ++g) gs[g] = 0;
    } else if (i == NN) {
      for (int g = gid[NN - 1] + 1; g <= NG; ++g) gs[g] = NN;
    } else {
      int a = gid[i - 1], b2 = gid[i];
      for (int g = a + 1; g <= b2; ++g) gs[g] = i;
    }
  }
}

// ---------- parallel CSR segment assignment (replaces serial scan) ----------
// Wave-level inclusive scan of counts + ONE atomicAdd per wave on a global
// cursor. Segments are disjoint/contiguous but NOT in node order (not needed).
__global__ __launch_bounds__(256) void k_assign(const int* __restrict__ counts,
    int* __restrict__ row_beg, int* __restrict__ row_end, int* __restrict__ cursor,
    int* __restrict__ gcounter) {
  const int i = blockIdx.x * 256 + threadIdx.x;
  const int lane = threadIdx.x & 63;
  int cnt = (i < NN) ? counts[i] : 0;
  int pre = cnt;                              // inclusive scan over 64 lanes
#pragma unroll
  for (int d = 1; d < 64; d <<= 1) {
    int o = __shfl_up(pre, d);
    if (lane >= d) pre += o;
  }
  int total = __shfl(pre, 63);
  int excl = pre - cnt;
  int base = 0;
  if (lane == 63 && total > 0) base = atomicAdd(gcounter, total);
  base = __shfl(base, 63);
  if (i < NN) {
    int b = base + excl;
    row_beg[i] = b;
    row_end[i] = b + cnt;
    cursor[i] = b;
  }
}

// ---------- P3: blocks 0..2499 layer-1 GEMM pair | 2500..3749 CSR scatter ----------
__global__ __launch_bounds__(256) void k_scatpair(const float* __restrict__ A,
    const float* __restrict__ Ws, const float* __restrict__ bs,
    const float* __restrict__ Wd, const float* __restrict__ bd,
    ushort_t* __restrict__ fsb, float* __restrict__ fd,
    const int* __restrict__ dst, const int* __restrict__ src,
    int* __restrict__ cursor, int* __restrict__ src_sorted) {
  const int bid = blockIdx.x;
  if (bid < 2 * (NN / 16)) {
    pair_tile(A, Ws, bs, Wd, bd, fsb, fd, bid);
  } else {
    int e = (bid - 2 * (NN / 16)) * 256 + threadIdx.x;
    int p = atomicAdd(&cursor[dst[e]], 1);
    src_sorted[p] = src[e];
  }
}

// ---------- layer-2 GEMM pair ----------
__global__ __launch_bounds__(256) void k_pair(const float* __restrict__ A,
    const float* __restrict__ Ws, const float* __restrict__ bs,
    const float* __restrict__ Wd, const float* __restrict__ bd,
    ushort_t* __restrict__ fsb, float* __restrict__ fd) {
  pair_tile(A, Ws, bs, Wd, bd, fsb, fd, blockIdx.x);
}

// ---------- fused GATv2: ONE WAVE PER NODE, lane = 8 contiguous bf16 feats --------
__global__ __launch_bounds__(256) void k_gat(const ushort_t* __restrict__ fsb,
    const float* __restrict__ fd, const int* __restrict__ src_sorted,
    const int* __restrict__ row_beg, const int* __restrict__ row_end,
    const float* __restrict__ attn, const float* __restrict__ bias,
    float* __restrict__ hout, int do_relu) {
  const int lane = threadIdx.x & 63;
  const int v = blockIdx.x * 4 + (threadIdx.x >> 6);
  const int fi = lane * 8;                    // head = lane>>3
  float fdv[8], av[8];
  *(float4*)&fdv[0] = *(const float4*)&fd[(size_t)v * HD + fi];
  *(float4*)&fdv[4] = *(const float4*)&fd[(size_t)v * HD + fi + 4];
  *(float4*)&av[0]  = *(const float4*)&attn[fi];
  *(float4*)&av[4]  = *(const float4*)&attn[fi + 4];
  int e = row_beg[v];
  const int end = row_end[v];
  float m = -3.4e38f, sum = 0.f;
  float acc[8];
#pragma unroll
  for (int i = 0; i < 8; ++i) acc[i] = 0.f;
  for (; e + 1 < end; e += 2) {               // 2 edges per iter
    int sA = src_sorted[e], sB = src_sorted[e + 1];
    uint4 uA = *(const uint4*)&fsb[(size_t)sA * HD + fi];
    uint4 uB = *(const uint4*)&fsb[(size_t)sB * HD + fi];
    float fA[8], fB[8];
    fA[0] = __uint_as_float(uA.x << 16); fA[1] = __uint_as_float(uA.x & 0xffff0000u);
    fA[2] = __uint_as_float(uA.y << 16); fA[3] = __uint_as_float(uA.y & 0xffff0000u);
    fA[4] = __uint_as_float(uA.z << 16); fA[5] = __uint_as_float(uA.z & 0xffff0000u);
    fA[6] = __uint_as_float(uA.w << 16); fA[7] = __uint_as_float(uA.w & 0xffff0000u);
    fB[0] = __uint_as_float(uB.x << 16); fB[1] = __uint_as_float(uB.x & 0xffff0000u);
    fB[2] = __uint_as_float(uB.y << 16); fB[3] = __uint_as_float(uB.y & 0xffff0000u);
    fB[4] = __uint_as_float(uB.z << 16); fB[5] = __uint_as_float(uB.z & 0xffff0000u);
    fB[6] = __uint_as_float(uB.w << 16); fB[7] = __uint_as_float(uB.w & 0xffff0000u);
    float pA = 0.f, pB = 0.f;
#pragma unroll
    for (int i = 0; i < 8; ++i) {
      float xA = fA[i] + fdv[i];
      float lA = fmaxf(xA, 0.f) + 0.2f * fminf(xA, 0.f);
      pA = fmaf(av[i], lA, pA);
      float xB = fB[i] + fdv[i];
      float lB = fmaxf(xB, 0.f) + 0.2f * fminf(xB, 0.f);
      pB = fmaf(av[i], lB, pB);
    }
    pA += swz<0x041F>(pA); pB += swz<0x041F>(pB);   // xor 1
    pA += swz<0x081F>(pA); pB += swz<0x081F>(pB);   // xor 2
    pA += swz<0x101F>(pA); pB += swz<0x101F>(pB);   // xor 4
    float mn = fmaxf(m, fmaxf(pA, pB));
    float scale = __expf(m - mn);
    float wA = __expf(pA - mn), wB = __expf(pB - mn);
    sum = fmaf(sum, scale, wA + wB);
#pragma unroll
    for (int i = 0; i < 8; ++i)
      acc[i] = fmaf(acc[i], scale, fmaf(wA, fA[i], wB * fB[i]));
    m = mn;
  }
  if (e < end) {                              // tail edge (wave-uniform)
    int sA = src_sorted[e];
    uint4 uA = *(const uint4*)&fsb[(size_t)sA * HD + fi];
    float fA[8];
    fA[0] = __uint_as_float(uA.x << 16); fA[1] = __uint_as_float(uA.x & 0xffff0000u);
    fA[2] = __uint_as_float(uA.y << 16); fA[3] = __uint_as_float(uA.y & 0xffff0000u);
    fA[4] = __uint_as_float(uA.z << 16); fA[5] = __uint_as_float(uA.z & 0xffff0000u);
    fA[6] = __uint_as_float(uA.w << 16); fA[7] = __uint_as_float(uA.w & 0xffff0000u);
    float pA = 0.f;
#pragma unroll
    for (int i = 0; i < 8; ++i) {
      float xA = fA[i] + fdv[i];
      float lA = fmaxf(xA, 0.f) + 0.2f * fminf(xA, 0.f);
      pA = fmaf(av[i], lA, pA);
    }
    pA += swz<0x041F>(pA);
    pA += swz<0x081F>(pA);
    pA += swz<0x101F>(pA);
    float mn = fmaxf(m, pA);
    float scale = __expf(m - mn);
    float wA = __expf(pA - mn);
    sum = fmaf(sum, scale, wA);
#pragma unroll
    for (int i = 0; i < 8; ++i)
      acc[i] = fmaf(acc[i], scale, wA * fA[i]);
  }
  float inv = 1.f / fmaxf(sum, 1e-9f);
  float outv[8];
#pragma unroll
  for (int i = 0; i < 8; ++i) outv[i] = fmaf(acc[i], inv, bias[fi + i]);
  // head-mean: sum across stride-8 lanes (same feat class), then /8
#pragma unroll
  for (int i = 0; i < 8; ++i) {
    outv[i] += swz<0x201F>(outv[i]);          // xor 8
    outv[i] += swz<0x401F>(outv[i]);          // xor 16
    outv[i] += __shfl_xor(outv[i], 32);
    outv[i] *= 0.125f;
    if (do_relu) outv[i] = fmaxf(outv[i], 0.f);
  }
  if (lane < 8) {                             // lane c holds feats 8c..8c+7
    *(float4*)&hout[(size_t)v * DH + lane * 8]     = make_float4(outv[0], outv[1], outv[2], outv[3]);
    *(float4*)&hout[(size_t)v * DH + lane * 8 + 4] = make_float4(outv[4], outv[5], outv[6], outv[7]);
  }
}

// ---------- per-graph mean + MLP head + softmax ----------
__global__ __launch_bounds__(256) void k_head(const float* __restrict__ h2,
    const int* __restrict__ gsv, const float* __restrict__ Wh1,
    const float* __restrict__ bh1, const float* __restrict__ Wh2,
    const float* __restrict__ bh2, float* __restrict__ out) {
  __shared__ float part[4][DH];
  __shared__ float hg[DH];
  __shared__ float hid[DH];
  __shared__ float logits[NC];
  const int g = blockIdx.x;
  const int t = threadIdx.x;
  const int f = t & 63, chunk = t >> 6;
  int start = gsv[g], stop = gsv[g + 1];
  float s = 0.f;
  for (int r = start + chunk; r < stop; r += 4) s += h2[(size_t)r * DH + f];
  part[chunk][f] = s;
  __syncthreads();
  if (t < DH) {
    float tot = part[0][t] + part[1][t] + part[2][t] + part[3][t];
    hg[t] = tot / fmaxf((float)(stop - start), 1.f);
  }
  __syncthreads();
  if (t < DH) {
    float a = 0.f;
    for (int k = 0; k < DH; ++k) a += hg[k] * Wh1[k * DH + t];
    hid[t] = fmaxf(a + bh1[t], 0.f);
  }
  __syncthreads();
  if (t < NC) {
    float l = 0.f;
    for (int k = 0; k < DH; ++k) l += hid[k] * Wh2[k * NC + t];
    logits[t] = l + bh2[t];
  }
  __syncthreads();
  if (t == 0) {
    float mx = logits[0];
    for (int i = 1; i < NC; ++i) mx = fmaxf(mx, logits[i]);
    float sm = 0.f;
    for (int i = 0; i < NC; ++i) {
      float wv = __expf(logits[i] - mx);
      logits[i] = wv;
      sm += wv;
    }
    float inv = 1.f / sm;
    for (int i = 0; i < NC; ++i) out[g * NC + i] = logits[i] * inv;
  }
}

extern "C" void kernel_launch(void* const* d_in, const int* in_sizes, int n_in,
                              void* d_out, int out_size, void* d_ws, size_t ws_size,
                              hipStream_t stream) {
  const float* g_feats = (const float*)d_in[0];
  const int*   src     = (const int*)d_in[1];
  const int*   dst     = (const int*)d_in[2];
  const int*   gid     = (const int*)d_in[3];
  const float* W_in    = (const float*)d_in[4];
  const float* b_in    = (const float*)d_in[5];
  const float* Wsrc1   = (const float*)d_in[6];
  const float* bsrc1   = (const float*)d_in[7];
  const float* Wdst1   = (const float*)d_in[8];
  const float* bdst1   = (const float*)d_in[9];
  const float* attn1   = (const float*)d_in[10];
  const float* bias1   = (const float*)d_in[11];
  const float* Wsrc2   = (const float*)d_in[12];
  const float* bsrc2   = (const float*)d_in[13];
  const float* Wdst2   = (const float*)d_in[14];
  const float* bdst2   = (const float*)d_in[15];
  const float* attn2   = (const float*)d_in[16];
  const float* bias2   = (const float*)d_in[17];
  const float* Wh1     = (const float*)d_in[18];
  const float* bh1     = (const float*)d_in[19];
  const float* Wh2     = (const float*)d_in[20];
  const float* bh2     = (const float*)d_in[21];

  char* ws = (char*)d_ws;
  size_t off = 0;
  auto A = [&](size_t bytes) -> char* {
    char* q = ws + off;
    off = (off + bytes + 255) & ~(size_t)255;
    return q;
  };
  float*    h0         = (float*)A((size_t)NN * DH * 4);
  float*    h1         = (float*)A((size_t)NN * DH * 4);
  float*    h2         = (float*)A((size_t)NN * DH * 4);
  ushort_t* fsb        = (ushort_t*)A((size_t)NN * HD * 2);
  float*    fd         = (float*)A((size_t)NN * HD * 4);
  int*      row_beg    = (int*)A((size_t)NN * 4);
  int*      row_end    = (int*)A((size_t)NN * 4);
  int*      cursor     = (int*)A((size_t)NN * 4);
  int*      src_sorted = (int*)A((size_t)NE * 4);
  int*      gs         = (int*)A((size_t)(NG + 1) * 4);
  int*      counts     = (int*)A((size_t)(NN + 1) * 4);  // +1: gcounter at [NN]

  const int nb16 = NN / 16;                   // 1250
  const int histb = NE / 256;                 // 1250
  const int gbb = (NN + 256) / 256;           // 79

  hipMemsetAsync(counts, 0, (size_t)(NN + 1) * 4, stream);

  k_pre<<<nb16 + histb + gbb, 256, 0, stream>>>(g_feats, W_in, b_in, h0,
                                                dst, counts, gid, gs);
  k_assign<<<(NN + 255) / 256, 256, 0, stream>>>(counts, row_beg, row_end,
                                                 cursor, &counts[NN]);
  k_scatpair<<<2 * nb16 + histb, 256, 0, stream>>>(h0, Wsrc1, bsrc1, Wdst1, bdst1,
                                                   fsb, fd, dst, src, cursor, src_sorted);
  k_gat<<<NN / 4, 256, 0, stream>>>(fsb, fd, src_sorted, row_beg, row_end,
                                    attn1, bias1, h1, 1);
  k_pair<<<2 * nb16, 256, 0, stream>>>(h1, Wsrc2, bsrc2, Wdst2, bdst2, fsb, fd);
  k_gat<<<NN / 4, 256, 0, stream>>>(fsb, fd, src_sorted, row_beg, row_end,
                                    attn2, bias2, h2, 0);
  k_head<<<NG, 256, 0, stream>>>(h2, gs, Wh1, bh1, Wh2, bh2, (float*)d_out);
}